// Round 1
// baseline (2393.120 us; speedup 1.0000x reference)
//
#include <hip/hip_runtime.h>
#include <stddef.h>

#define BATCH 16
#define CH    256
#define NPIX  4096
#define DQH   64
#define L2E   1.44269504088896340736f

typedef __attribute__((ext_vector_type(8))) short bf16x8;
typedef __attribute__((ext_vector_type(4))) float floatx4;

__device__ __forceinline__ unsigned short f2bf(float f) {
  union { float f; unsigned int u; } v; v.f = f;
  unsigned int u = v.u;
  u += 0x7fffu + ((u >> 16) & 1u);   // RNE
  return (unsigned short)(u >> 16);
}

__device__ __forceinline__ bf16x8 ldbf8(const unsigned short* p) {
  return *(const bf16x8*)p;
}

// ---------------------------------------------------------------------------
// Kernel 1: QKV projection (1x1 conv). z=0 -> Q, z=1 -> K, z=2..5 -> V quarter.
// Q,K stored bf16 [b][pixel][d] (d contiguous), V stored bf16 [b][c][pixel].
// ---------------------------------------------------------------------------
__global__ __launch_bounds__(256) void proj_kernel(
    const float* __restrict__ xq, const float* __restrict__ xk,
    const float* __restrict__ xv,
    const float* __restrict__ Wq, const float* __restrict__ bq,
    const float* __restrict__ Wk, const float* __restrict__ bk,
    const float* __restrict__ Wv, const float* __restrict__ bv,
    unsigned short* __restrict__ Qb, unsigned short* __restrict__ Kb,
    unsigned short* __restrict__ Vb) {
  __shared__ unsigned short tile[64][66];   // +2 pad -> conflict-free transpose
  const int t  = threadIdx.x;
  const int px = t & 63;        // lane = pixel (coalesced x loads)
  const int w  = t >> 6;        // wave id
  const int b  = blockIdx.y;
  const int pxbase = blockIdx.x * 64;
  const int z  = blockIdx.z;

  const float* X; const float* Wt; const float* bt; int dbase;
  if (z == 0)      { X = xq; Wt = Wq; bt = bq; dbase = 0; }
  else if (z == 1) { X = xk; Wt = Wk; bt = bk; dbase = 0; }
  else             { X = xv; Wt = Wv; bt = bv; dbase = (z - 2) * 64; }

  float acc[16];
#pragma unroll
  for (int s = 0; s < 16; ++s) acc[s] = bt[dbase + w + 4 * s];

  const float* xp = X + (size_t)b * CH * NPIX + pxbase + px;
  for (int c4 = 0; c4 < CH / 4; ++c4) {
    const float x0 = xp[(size_t)(c4 * 4 + 0) * NPIX];
    const float x1 = xp[(size_t)(c4 * 4 + 1) * NPIX];
    const float x2 = xp[(size_t)(c4 * 4 + 2) * NPIX];
    const float x3 = xp[(size_t)(c4 * 4 + 3) * NPIX];
#pragma unroll
    for (int s = 0; s < 16; ++s) {
      const float4 w4 = *(const float4*)&Wt[(size_t)(dbase + w + 4 * s) * CH + c4 * 4];
      acc[s] = fmaf(w4.x, x0, acc[s]);
      acc[s] = fmaf(w4.y, x1, acc[s]);
      acc[s] = fmaf(w4.z, x2, acc[s]);
      acc[s] = fmaf(w4.w, x3, acc[s]);
    }
  }

  if (z >= 2) {
    // V layout [b][c][pixel]: lane=pixel is already coalesced
#pragma unroll
    for (int s = 0; s < 16; ++s)
      Vb[((size_t)b * CH + dbase + w + 4 * s) * NPIX + pxbase + px] = f2bf(acc[s]);
  } else {
    // Q/K layout [b][pixel][d]: transpose through LDS for coalesced writes
#pragma unroll
    for (int s = 0; s < 16; ++s) tile[px][w + 4 * s] = f2bf(acc[s]);
    __syncthreads();
    unsigned short* Ob = (z == 0) ? Qb : Kb;
    const int row  = t >> 2;
    const int col0 = (t & 3) * 16;
    unsigned int* dst =
        (unsigned int*)(Ob + ((size_t)b * NPIX + pxbase + row) * DQH + col0);
#pragma unroll
    for (int e = 0; e < 8; ++e)
      dst[e] = *(const unsigned int*)&tile[row][col0 + 2 * e];
  }
}

// ---------------------------------------------------------------------------
// Kernel 2: per-row softmax stats. s_j = max_i E[j,i] + ln(sum_i exp(E-max)).
// Block = (64 j-rows, one batch); wave w owns rows [w*16, w*16+16).
// ---------------------------------------------------------------------------
__global__ __launch_bounds__(256) void pass1_kernel(
    const unsigned short* __restrict__ Qb, const unsigned short* __restrict__ Kb,
    float* __restrict__ Srow) {
  const int t    = threadIdx.x;
  const int lane = t & 63;
  const int w    = t >> 6;
  const int l15  = lane & 15;
  const int quad = lane >> 4;
  const int b    = blockIdx.y;
  const int jbase = blockIdx.x * 64 + w * 16;

  // A fragments (rows j = jbase + l15), loop-invariant
  const unsigned short* qrow = Qb + ((size_t)b * NPIX + jbase + l15) * DQH;
  const bf16x8 qA0 = ldbf8(qrow + quad * 8);
  const bf16x8 qA1 = ldbf8(qrow + 32 + quad * 8);

  float m_run[4], l_run[4];
#pragma unroll
  for (int r = 0; r < 4; ++r) { m_run[r] = -1e30f; l_run[r] = 0.0f; }

  const unsigned short* kbase = Kb + (size_t)b * NPIX * DQH;
  for (int ib = 0; ib < NPIX; ib += 64) {
    floatx4 e[4];
#pragma unroll
    for (int nt = 0; nt < 4; ++nt) {
      const unsigned short* krow = kbase + (size_t)(ib + nt * 16 + l15) * DQH;
      const bf16x8 kB0 = ldbf8(krow + quad * 8);
      const bf16x8 kB1 = ldbf8(krow + 32 + quad * 8);
      floatx4 a = {0.f, 0.f, 0.f, 0.f};
      a = __builtin_amdgcn_mfma_f32_16x16x32_bf16(qA0, kB0, a, 0, 0, 0);
      a = __builtin_amdgcn_mfma_f32_16x16x32_bf16(qA1, kB1, a, 0, 0, 0);
      e[nt] = a;
    }
#pragma unroll
    for (int r = 0; r < 4; ++r) {
      float mx = fmaxf(fmaxf(e[0][r], e[1][r]), fmaxf(e[2][r], e[3][r]));
      mx = fmaxf(mx, __shfl_xor(mx, 1));
      mx = fmaxf(mx, __shfl_xor(mx, 2));
      mx = fmaxf(mx, __shfl_xor(mx, 4));
      mx = fmaxf(mx, __shfl_xor(mx, 8));
      const float mnew = fmaxf(m_run[r], mx);
      float p = exp2f((e[0][r] - mnew) * L2E) + exp2f((e[1][r] - mnew) * L2E)
              + exp2f((e[2][r] - mnew) * L2E) + exp2f((e[3][r] - mnew) * L2E);
      p += __shfl_xor(p, 1);
      p += __shfl_xor(p, 2);
      p += __shfl_xor(p, 4);
      p += __shfl_xor(p, 8);
      l_run[r] = l_run[r] * exp2f((m_run[r] - mnew) * L2E) + p;
      m_run[r] = mnew;
    }
  }
  if (l15 == 0) {
#pragma unroll
    for (int r = 0; r < 4; ++r)
      Srow[(size_t)b * NPIX + jbase + quad * 4 + r] = m_run[r] + logf(l_run[r]);
  }
}

// ---------------------------------------------------------------------------
// Kernel 3: out[:, i-tile] = sum_j exp(E[j,i]-s_j) * v[:,j].
// Block = (batch, 64-i tile), 4 waves; wave w owns c in [w*64, w*64+64) and
// computes the E columns i in [ibase+w*16, +16). P goes through a transposed
// LDS tile (stride 40 ushorts -> rows 16B-aligned for ds_read_b128).
// ---------------------------------------------------------------------------
__global__ __launch_bounds__(256) void pass2_kernel(
    const unsigned short* __restrict__ Qb, const unsigned short* __restrict__ Kb,
    const unsigned short* __restrict__ Vb, const float* __restrict__ Srow,
    float* __restrict__ out) {
  __shared__ __attribute__((aligned(16))) unsigned short Plds[64][40];
  const int t    = threadIdx.x;
  const int lane = t & 63;
  const int w    = t >> 6;
  const int l15  = lane & 15;
  const int quad = lane >> 4;
  const int b    = blockIdx.y;
  const int ibase = blockIdx.x * 64;

  // K fragments for this block's i-range: loop-invariant, hoisted
  const unsigned short* krow = Kb + ((size_t)b * NPIX + ibase + w * 16 + l15) * DQH;
  const bf16x8 kB0 = ldbf8(krow + quad * 8);
  const bf16x8 kB1 = ldbf8(krow + 32 + quad * 8);

  floatx4 accO[4][4];
#pragma unroll
  for (int mt = 0; mt < 4; ++mt)
#pragma unroll
    for (int nt = 0; nt < 4; ++nt)
      accO[mt][nt] = (floatx4){0.f, 0.f, 0.f, 0.f};

  const float* sp          = Srow + (size_t)b * NPIX;
  const unsigned short* qb = Qb + (size_t)b * NPIX * DQH;
  const unsigned short* vb = Vb + (size_t)b * CH * NPIX;

  for (int jb = 0; jb < NPIX; jb += 32) {
#pragma unroll
    for (int jt = 0; jt < 2; ++jt) {
      const unsigned short* qrow = qb + (size_t)(jb + jt * 16 + l15) * DQH;
      const bf16x8 qA0 = ldbf8(qrow + quad * 8);
      const bf16x8 qA1 = ldbf8(qrow + 32 + quad * 8);
      floatx4 a = {0.f, 0.f, 0.f, 0.f};
      a = __builtin_amdgcn_mfma_f32_16x16x32_bf16(qA0, kB0, a, 0, 0, 0);
      a = __builtin_amdgcn_mfma_f32_16x16x32_bf16(qA1, kB1, a, 0, 0, 0);
      const int jrow = jb + jt * 16 + quad * 4;
      const unsigned int p0 = f2bf(exp2f((a[0] - sp[jrow + 0]) * L2E));
      const unsigned int p1 = f2bf(exp2f((a[1] - sp[jrow + 1]) * L2E));
      const unsigned int p2 = f2bf(exp2f((a[2] - sp[jrow + 2]) * L2E));
      const unsigned int p3 = f2bf(exp2f((a[3] - sp[jrow + 3]) * L2E));
      uint2 pk;
      pk.x = p0 | (p1 << 16);
      pk.y = p2 | (p3 << 16);
      // transposed: Plds[i_local][j_local], 4 consecutive j per lane -> b64
      *(uint2*)&Plds[w * 16 + l15][jt * 16 + quad * 4] = pk;
    }
    __syncthreads();

    bf16x8 pB[4];
#pragma unroll
    for (int nt = 0; nt < 4; ++nt)
      pB[nt] = ldbf8(&Plds[nt * 16 + l15][quad * 8]);
#pragma unroll
    for (int mt = 0; mt < 4; ++mt) {
      const unsigned short* vrow =
          vb + (size_t)(w * 64 + mt * 16 + l15) * NPIX + jb;
      const bf16x8 vA = ldbf8(vrow + quad * 8);
#pragma unroll
      for (int nt = 0; nt < 4; ++nt)
        accO[mt][nt] =
            __builtin_amdgcn_mfma_f32_16x16x32_bf16(vA, pB[nt], accO[mt][nt], 0, 0, 0);
    }
    __syncthreads();
  }

#pragma unroll
  for (int mt = 0; mt < 4; ++mt) {
#pragma unroll
    for (int nt = 0; nt < 4; ++nt) {
#pragma unroll
      for (int r = 0; r < 4; ++r) {
        const int c = w * 64 + mt * 16 + quad * 4 + r;
        const int i = ibase + nt * 16 + l15;
        out[((size_t)b * CH + c) * NPIX + i] = accO[mt][nt][r];
      }
    }
  }
}

// ---------------------------------------------------------------------------
extern "C" void kernel_launch(void* const* d_in, const int* in_sizes, int n_in,
                              void* d_out, int out_size, void* d_ws, size_t ws_size,
                              hipStream_t stream) {
  (void)in_sizes; (void)n_in; (void)out_size; (void)ws_size;
  const float* xq = (const float*)d_in[0];
  const float* xk = (const float*)d_in[1];
  const float* xv = (const float*)d_in[2];
  const float* Wq = (const float*)d_in[3];
  const float* bq = (const float*)d_in[4];
  const float* Wk = (const float*)d_in[5];
  const float* bk = (const float*)d_in[6];
  const float* Wv = (const float*)d_in[7];
  const float* bv = (const float*)d_in[8];
  float* out = (float*)d_out;

  // workspace layout (bytes):
  //   Qb bf16 [16][4096][64]   @ 0         (8 MiB)
  //   Kb bf16 [16][4096][64]   @ 8 MiB     (8 MiB)
  //   Vb bf16 [16][256][4096]  @ 16 MiB    (32 MiB)
  //   Srow f32 [16][4096]      @ 48 MiB    (256 KiB)
  char* ws = (char*)d_ws;
  const size_t qk_bytes = (size_t)BATCH * NPIX * DQH * 2;   // 8 MiB
  const size_t v_bytes  = (size_t)BATCH * CH * NPIX * 2;    // 32 MiB
  unsigned short* Qb = (unsigned short*)(ws);
  unsigned short* Kb = (unsigned short*)(ws + qk_bytes);
  unsigned short* Vb = (unsigned short*)(ws + 2 * qk_bytes);
  float* Srow        = (float*)(ws + 2 * qk_bytes + v_bytes);

  proj_kernel<<<dim3(64, 16, 6), 256, 0, stream>>>(xq, xk, xv, Wq, bq, Wk, bk,
                                                   Wv, bv, Qb, Kb, Vb);
  pass1_kernel<<<dim3(64, 16), 256, 0, stream>>>(Qb, Kb, Srow);
  pass2_kernel<<<dim3(64, 16), 256, 0, stream>>>(Qb, Kb, Vb, Srow, out);
}

// Round 2
// 962.834 us; speedup vs baseline: 2.4855x; 2.4855x over previous
//
#include <hip/hip_runtime.h>
#include <hip/hip_bf16.h>
#include <stddef.h>

#define BATCH 16
#define CH    256
#define NPIX  4096
#define DQH   64
#define L2E   1.44269504088896340736f

typedef __attribute__((ext_vector_type(8))) short bf16x8;
typedef __attribute__((ext_vector_type(4))) float floatx4;

__device__ __forceinline__ unsigned short f2bf(float f) {
  union { float f; unsigned int u; } v; v.f = f;
  unsigned int u = v.u;
  u += 0x7fffu + ((u >> 16) & 1u);   // RNE
  return (unsigned short)(u >> 16);
}

__device__ __forceinline__ unsigned int pk2bf(float a, float b) {
  __hip_bfloat162 h = __float22bfloat162_rn(float2{a, b});
  union { __hip_bfloat162 h; unsigned int u; } cv;
  cv.h = h;
  return cv.u;
}

__device__ __forceinline__ bf16x8 ldbf8(const unsigned short* p) {
  return *(const bf16x8*)p;
}

// ---------------------------------------------------------------------------
// Kernel 0: convert W matrices to bf16, rows: [0,64)=Wq, [64,128)=Wk,
// [128,384)=Wv. 384x256 elements.
// ---------------------------------------------------------------------------
__global__ __launch_bounds__(256) void wconv_kernel(
    const float* __restrict__ Wq, const float* __restrict__ Wk,
    const float* __restrict__ Wv, unsigned short* __restrict__ Wb) {
  const int idx = blockIdx.x * 256 + threadIdx.x;   // < 98304
  float v;
  if (idx < 64 * CH)            v = Wq[idx];
  else if (idx < 128 * CH)      v = Wk[idx - 64 * CH];
  else                          v = Wv[idx - 128 * CH];
  Wb[idx] = f2bf(v);
}

// ---------------------------------------------------------------------------
// Kernel 1: QKV projection as MFMA GEMM. Block = 64 outch x 256 px, one
// batch, z slice (0=Q,1=K,2..5=V quarters). x tile staged fp32 in LDS,
// B-fragments packed to bf16 on read; A-fragments direct from bf16 W.
// ---------------------------------------------------------------------------
__global__ __launch_bounds__(256) void proj_kernel(
    const float* __restrict__ xq, const float* __restrict__ xk,
    const float* __restrict__ xv, const unsigned short* __restrict__ Wb,
    const float* __restrict__ bq, const float* __restrict__ bk,
    const float* __restrict__ bv,
    unsigned short* __restrict__ Qb, unsigned short* __restrict__ Kb,
    unsigned short* __restrict__ Vb) {
  __shared__ __attribute__((aligned(16))) float xtile[32][260];  // 33.3 KB
  const int t    = threadIdx.x;
  const int lane = t & 63;
  const int w    = t >> 6;
  const int l15  = lane & 15;
  const int quad = lane >> 4;
  const int b    = blockIdx.y;
  const int pxbase = blockIdx.x * 256;
  const int z    = blockIdx.z;

  const float* X; const float* bt; int dbase; int wbase;
  if (z == 0)      { X = xq; bt = bq; dbase = 0;            wbase = 0; }
  else if (z == 1) { X = xk; bt = bk; dbase = 0;            wbase = 64; }
  else             { X = xv; bt = bv; dbase = (z - 2) * 64; wbase = 128 + (z - 2) * 64; }

  floatx4 acc[4][4];
#pragma unroll
  for (int mt = 0; mt < 4; ++mt)
#pragma unroll
    for (int nt = 0; nt < 4; ++nt)
      acc[mt][nt] = (floatx4){0.f, 0.f, 0.f, 0.f};

  const int px4 = (t & 63) * 4;
  const float* xbase = X + (size_t)b * CH * NPIX + pxbase + px4;

  for (int kb = 0; kb < 8; ++kb) {
    // stage x[kb*32 .. +32][pxbase .. +256] fp32 -> LDS (coalesced float4)
#pragma unroll
    for (int i = 0; i < 8; ++i) {
      const int cloc = w + i * 4;
      const float4 xv4 = *(const float4*)(xbase + (size_t)(kb * 32 + cloc) * NPIX);
      *(float4*)&xtile[cloc][px4] = xv4;
    }
    __syncthreads();

#pragma unroll
    for (int nt = 0; nt < 4; ++nt) {
      // build B fragment: pixel = w*64 + nt*16 + l15, k = quad*8 + j
      const int pxl = w * 64 + nt * 16 + l15;
      float f[8];
#pragma unroll
      for (int j = 0; j < 8; ++j) f[j] = xtile[quad * 8 + j][pxl];
      union { bf16x8 v; unsigned int u[4]; } bb;
      bb.u[0] = pk2bf(f[0], f[1]);
      bb.u[1] = pk2bf(f[2], f[3]);
      bb.u[2] = pk2bf(f[4], f[5]);
      bb.u[3] = pk2bf(f[6], f[7]);
#pragma unroll
      for (int mt = 0; mt < 4; ++mt) {
        const bf16x8 aA =
            ldbf8(Wb + (size_t)(wbase + mt * 16 + l15) * CH + kb * 32 + quad * 8);
        acc[mt][nt] =
            __builtin_amdgcn_mfma_f32_16x16x32_bf16(aA, bb.v, acc[mt][nt], 0, 0, 0);
      }
    }
    __syncthreads();
  }

  // epilogue: C-layout col=l15 (pixel), row=quad*4+r (outch)
  float4 bias4[4];
#pragma unroll
  for (int mt = 0; mt < 4; ++mt)
    bias4[mt] = *(const float4*)&bt[dbase + mt * 16 + quad * 4];

  if (z >= 2) {
    // V layout [b][c][pixel]
#pragma unroll
    for (int mt = 0; mt < 4; ++mt)
#pragma unroll
      for (int nt = 0; nt < 4; ++nt) {
        const int px = pxbase + w * 64 + nt * 16 + l15;
#pragma unroll
        for (int r = 0; r < 4; ++r) {
          const int c = dbase + mt * 16 + quad * 4 + r;
          Vb[((size_t)b * CH + c) * NPIX + px] =
              f2bf(acc[mt][nt][r] + ((const float*)&bias4[mt])[r]);
        }
      }
  } else {
    // Q/K layout [b][pixel][d]: lane packs 4 consecutive d -> b64 store
    unsigned short* Ob = (z == 0) ? Qb : Kb;
#pragma unroll
    for (int mt = 0; mt < 4; ++mt)
#pragma unroll
      for (int nt = 0; nt < 4; ++nt) {
        const int px = pxbase + w * 64 + nt * 16 + l15;
        uint2 qp;
        qp.x = pk2bf(acc[mt][nt][0] + ((const float*)&bias4[mt])[0],
                     acc[mt][nt][1] + ((const float*)&bias4[mt])[1]);
        qp.y = pk2bf(acc[mt][nt][2] + ((const float*)&bias4[mt])[2],
                     acc[mt][nt][3] + ((const float*)&bias4[mt])[3]);
        *(uint2*)&Ob[((size_t)b * NPIX + px) * DQH + mt * 16 + quad * 4] = qp;
      }
  }
}

// ---------------------------------------------------------------------------
// Kernel 2: per-row softmax stats. s_j = max_i E[j,i] + ln(sum_i exp(E-max)).
// ---------------------------------------------------------------------------
__global__ __launch_bounds__(256) void pass1_kernel(
    const unsigned short* __restrict__ Qb, const unsigned short* __restrict__ Kb,
    float* __restrict__ Srow) {
  const int t    = threadIdx.x;
  const int lane = t & 63;
  const int w    = t >> 6;
  const int l15  = lane & 15;
  const int quad = lane >> 4;
  const int b    = blockIdx.y;
  const int jbase = blockIdx.x * 64 + w * 16;

  const unsigned short* qrow = Qb + ((size_t)b * NPIX + jbase + l15) * DQH;
  const bf16x8 qA0 = ldbf8(qrow + quad * 8);
  const bf16x8 qA1 = ldbf8(qrow + 32 + quad * 8);

  float m_run[4], l_run[4];
#pragma unroll
  for (int r = 0; r < 4; ++r) { m_run[r] = -1e30f; l_run[r] = 0.0f; }

  const unsigned short* kbase = Kb + (size_t)b * NPIX * DQH;
  for (int ib = 0; ib < NPIX; ib += 64) {
    floatx4 e[4];
#pragma unroll
    for (int nt = 0; nt < 4; ++nt) {
      const unsigned short* krow = kbase + (size_t)(ib + nt * 16 + l15) * DQH;
      const bf16x8 kB0 = ldbf8(krow + quad * 8);
      const bf16x8 kB1 = ldbf8(krow + 32 + quad * 8);
      floatx4 a = {0.f, 0.f, 0.f, 0.f};
      a = __builtin_amdgcn_mfma_f32_16x16x32_bf16(qA0, kB0, a, 0, 0, 0);
      a = __builtin_amdgcn_mfma_f32_16x16x32_bf16(qA1, kB1, a, 0, 0, 0);
      e[nt] = a;
    }
#pragma unroll
    for (int r = 0; r < 4; ++r) {
      float mx = fmaxf(fmaxf(e[0][r], e[1][r]), fmaxf(e[2][r], e[3][r]));
      mx = fmaxf(mx, __shfl_xor(mx, 1));
      mx = fmaxf(mx, __shfl_xor(mx, 2));
      mx = fmaxf(mx, __shfl_xor(mx, 4));
      mx = fmaxf(mx, __shfl_xor(mx, 8));
      const float mnew = fmaxf(m_run[r], mx);
      float p = exp2f((e[0][r] - mnew) * L2E) + exp2f((e[1][r] - mnew) * L2E)
              + exp2f((e[2][r] - mnew) * L2E) + exp2f((e[3][r] - mnew) * L2E);
      p += __shfl_xor(p, 1);
      p += __shfl_xor(p, 2);
      p += __shfl_xor(p, 4);
      p += __shfl_xor(p, 8);
      l_run[r] = l_run[r] * exp2f((m_run[r] - mnew) * L2E) + p;
      m_run[r] = mnew;
    }
  }
  if (l15 == 0) {
#pragma unroll
    for (int r = 0; r < 4; ++r)
      Srow[(size_t)b * NPIX + jbase + quad * 4 + r] = m_run[r] + logf(l_run[r]);
  }
}

// ---------------------------------------------------------------------------
// Kernel 3: out[:, i-tile] = sum_j exp(E[j,i]-s_j) * v[:,j].
// j-step 64 (2 barriers per 64 j), Q fragments double-buffered.
// ---------------------------------------------------------------------------
__global__ __launch_bounds__(256) void pass2_kernel(
    const unsigned short* __restrict__ Qb, const unsigned short* __restrict__ Kb,
    const unsigned short* __restrict__ Vb, const float* __restrict__ Srow,
    float* __restrict__ out) {
  __shared__ __attribute__((aligned(16))) unsigned short Plds[64][72];  // 9 KB
  const int t    = threadIdx.x;
  const int lane = t & 63;
  const int w    = t >> 6;
  const int l15  = lane & 15;
  const int quad = lane >> 4;
  const int b    = blockIdx.y;
  const int ibase = blockIdx.x * 64;

  const unsigned short* krow = Kb + ((size_t)b * NPIX + ibase + w * 16 + l15) * DQH;
  const bf16x8 kB0 = ldbf8(krow + quad * 8);
  const bf16x8 kB1 = ldbf8(krow + 32 + quad * 8);

  floatx4 accO[4][4];
#pragma unroll
  for (int mt = 0; mt < 4; ++mt)
#pragma unroll
    for (int nt = 0; nt < 4; ++nt)
      accO[mt][nt] = (floatx4){0.f, 0.f, 0.f, 0.f};

  const float* sp          = Srow + (size_t)b * NPIX;
  const unsigned short* qb = Qb + (size_t)b * NPIX * DQH;
  const unsigned short* vb = Vb + (size_t)b * CH * NPIX;

  // prefetch Q fragments for jb = 0
  bf16x8 qA[4][2], qN[4][2];
#pragma unroll
  for (int jt = 0; jt < 4; ++jt) {
    const unsigned short* qrow = qb + (size_t)(jt * 16 + l15) * DQH;
    qA[jt][0] = ldbf8(qrow + quad * 8);
    qA[jt][1] = ldbf8(qrow + 32 + quad * 8);
  }

  for (int jb = 0; jb < NPIX; jb += 64) {
    // issue next-iteration Q loads (wrap on last iter; result unused)
    const int jn = (jb + 64) & (NPIX - 1);
#pragma unroll
    for (int jt = 0; jt < 4; ++jt) {
      const unsigned short* qrow = qb + (size_t)(jn + jt * 16 + l15) * DQH;
      qN[jt][0] = ldbf8(qrow + quad * 8);
      qN[jt][1] = ldbf8(qrow + 32 + quad * 8);
    }

    // E + P for 64 j rows (this wave's 16-i strip)
#pragma unroll
    for (int jt = 0; jt < 4; ++jt) {
      floatx4 a = {0.f, 0.f, 0.f, 0.f};
      a = __builtin_amdgcn_mfma_f32_16x16x32_bf16(qA[jt][0], kB0, a, 0, 0, 0);
      a = __builtin_amdgcn_mfma_f32_16x16x32_bf16(qA[jt][1], kB1, a, 0, 0, 0);
      const float4 s4 = *(const float4*)&sp[jb + jt * 16 + quad * 4];
      uint2 pk;
      pk.x = pk2bf(exp2f((a[0] - s4.x) * L2E), exp2f((a[1] - s4.y) * L2E));
      pk.y = pk2bf(exp2f((a[2] - s4.z) * L2E), exp2f((a[3] - s4.w) * L2E));
      *(uint2*)&Plds[w * 16 + l15][jt * 16 + quad * 4] = pk;
    }
    __syncthreads();

    // PV: acc[c, i] += V[c, jb..jb+64] * P
#pragma unroll
    for (int ks = 0; ks < 2; ++ks) {
      bf16x8 pB[4];
#pragma unroll
      for (int nt = 0; nt < 4; ++nt)
        pB[nt] = ldbf8(&Plds[nt * 16 + l15][ks * 32 + quad * 8]);
#pragma unroll
      for (int mt = 0; mt < 4; ++mt) {
        const unsigned short* vrow =
            vb + (size_t)(w * 64 + mt * 16 + l15) * NPIX + jb + ks * 32;
        const bf16x8 vA = ldbf8(vrow + quad * 8);
#pragma unroll
        for (int nt = 0; nt < 4; ++nt)
          accO[mt][nt] =
              __builtin_amdgcn_mfma_f32_16x16x32_bf16(vA, pB[nt], accO[mt][nt], 0, 0, 0);
      }
    }
    __syncthreads();

#pragma unroll
    for (int jt = 0; jt < 4; ++jt) {
      qA[jt][0] = qN[jt][0];
      qA[jt][1] = qN[jt][1];
    }
  }

#pragma unroll
  for (int mt = 0; mt < 4; ++mt) {
#pragma unroll
    for (int nt = 0; nt < 4; ++nt) {
#pragma unroll
      for (int r = 0; r < 4; ++r) {
        const int c = w * 64 + mt * 16 + quad * 4 + r;
        const int i = ibase + nt * 16 + l15;
        out[((size_t)b * CH + c) * NPIX + i] = accO[mt][nt][r];
      }
    }
  }
}

// ---------------------------------------------------------------------------
extern "C" void kernel_launch(void* const* d_in, const int* in_sizes, int n_in,
                              void* d_out, int out_size, void* d_ws, size_t ws_size,
                              hipStream_t stream) {
  (void)in_sizes; (void)n_in; (void)out_size; (void)ws_size;
  const float* xq = (const float*)d_in[0];
  const float* xk = (const float*)d_in[1];
  const float* xv = (const float*)d_in[2];
  const float* Wq = (const float*)d_in[3];
  const float* bq = (const float*)d_in[4];
  const float* Wk = (const float*)d_in[5];
  const float* bk = (const float*)d_in[6];
  const float* Wv = (const float*)d_in[7];
  const float* bv = (const float*)d_in[8];
  float* out = (float*)d_out;

  // workspace layout (bytes):
  //   Qb bf16 [16][4096][64]   @ 0          (8 MiB)
  //   Kb bf16 [16][4096][64]   @ 8 MiB      (8 MiB)
  //   Vb bf16 [16][256][4096]  @ 16 MiB     (32 MiB)
  //   Srow f32 [16][4096]      @ 48 MiB     (256 KiB)
  //   Wb bf16 [384][256]       @ 48.25 MiB  (192 KiB)
  char* ws = (char*)d_ws;
  const size_t qk_bytes = (size_t)BATCH * NPIX * DQH * 2;   // 8 MiB
  const size_t v_bytes  = (size_t)BATCH * CH * NPIX * 2;    // 32 MiB
  const size_t s_bytes  = (size_t)BATCH * NPIX * 4;         // 256 KiB
  unsigned short* Qb = (unsigned short*)(ws);
  unsigned short* Kb = (unsigned short*)(ws + qk_bytes);
  unsigned short* Vb = (unsigned short*)(ws + 2 * qk_bytes);
  float* Srow        = (float*)(ws + 2 * qk_bytes + v_bytes);
  unsigned short* Wb = (unsigned short*)(ws + 2 * qk_bytes + v_bytes + s_bytes);

  wconv_kernel<<<dim3(384), 256, 0, stream>>>(Wq, Wk, Wv, Wb);
  proj_kernel<<<dim3(16, 16, 6), 256, 0, stream>>>(xq, xk, xv, Wb, bq, bk, bv,
                                                   Qb, Kb, Vb);
  pass1_kernel<<<dim3(64, 16), 256, 0, stream>>>(Qb, Kb, Srow);
  pass2_kernel<<<dim3(64, 16), 256, 0, stream>>>(Qb, Kb, Vb, Srow, out);
}